// Round 6
// baseline (234.306 us; speedup 1.0000x reference)
//
#include <hip/hip_runtime.h>
#include <math.h>

#define B_    2
#define NSEQ  8192
#define DIM_  512
#define H_    8
#define DH_   64
#define F_    256
#define M_    (B_*NSEQ)      // 16384
#define QKV_  1536

typedef __attribute__((ext_vector_type(8))) short     short8;
typedef __attribute__((ext_vector_type(4))) float     float4v;
typedef __attribute__((ext_vector_type(8))) unsigned short ushort8v;

__device__ __forceinline__ unsigned short f2bf(float f) {
    unsigned u = __float_as_uint(f);
    u += 0x7FFFu + ((u >> 16) & 1u);   // RNE
    return (unsigned short)(u >> 16);
}
// pack two floats -> two bf16 (truncate; bias cancels in N/D ratio)
__device__ __forceinline__ unsigned pack2bf(float lo, float hi) {
    return __builtin_amdgcn_perm(__float_as_uint(hi), __float_as_uint(lo), 0x07060302);
}
__device__ __forceinline__ void glds16(const void* g, void* s) {
    __builtin_amdgcn_global_load_lds(
        (const __attribute__((address_space(1))) unsigned int*)g,
        (__attribute__((address_space(3))) unsigned int*)s, 16, 0, 0);
}

// ---------------------------------------------------------------------------
// fused fp32->bf16 for all 4 inputs, one launch.
// ---------------------------------------------------------------------------
__global__ __launch_bounds__(256) void cvt_all(const float* __restrict__ x,
                                               const float* __restrict__ wqkv,
                                               const float* __restrict__ wout,
                                               const float* __restrict__ proj,
                                               unsigned short* __restrict__ xb,
                                               unsigned short* __restrict__ wqkvb,
                                               unsigned short* __restrict__ woutb,
                                               unsigned short* __restrict__ projb) {
    int bid = blockIdx.x;
    const float* in; unsigned short* out; int i;
    if (bid < 4096)      { in = x;    out = xb;    i = bid * 256 + threadIdx.x; }
    else if (bid < 4480) { in = wqkv; out = wqkvb; i = (bid - 4096) * 256 + threadIdx.x; }
    else if (bid < 4608) { in = wout; out = woutb; i = (bid - 4480) * 256 + threadIdx.x; }
    else                 { in = proj; out = projb; i = (bid - 4608) * 256 + threadIdx.x; }
    float4 a = ((const float4*)in)[2 * i];
    float4 b = ((const float4*)in)[2 * i + 1];
    ushort8v o;
    o[0] = f2bf(a.x); o[1] = f2bf(a.y); o[2] = f2bf(a.z); o[3] = f2bf(a.w);
    o[4] = f2bf(b.x); o[5] = f2bf(b.y); o[6] = f2bf(b.z); o[7] = f2bf(b.w);
    ((ushort8v*)out)[i] = o;
}

// ---------------------------------------------------------------------------
// Reg-prefetch pipelined NT GEMM. 128x128 tile, BK=32, ping-pong LDS.
// KEY: staging is buffer_load -> VGPR -> ds_write (NOT global_load_lds), so
// the barrier needs only lgkmcnt; the k+2 global loads stay IN FLIGHT across
// the barrier (glds writes LDS and forces a vmcnt(0) drain — this doesn't).
// Unrolled x2 so the two staging reg sets have static indices (no scratch).
// XCD swizzle: flat%8 -> contiguous m-tile range per XCD (x-row L2 reuse).
// Requires: K%64==0, grid.x*grid.y%8==0.
// ---------------------------------------------------------------------------
template<bool BF16OUT>
__global__ __launch_bounds__(256) void gemm_nt_rp(const unsigned short* __restrict__ A,
                                                  const unsigned short* __restrict__ Bm,
                                                  const float* __restrict__ bias,
                                                  void* __restrict__ Cout,
                                                  int M, int N, int K) {
    __shared__ __align__(16) unsigned short As[2][128 * 32];
    __shared__ __align__(16) unsigned short Bs[2][128 * 32];
    const int t  = threadIdx.x;
    const int w  = t >> 6, l = t & 63;
    const int wm = w >> 1, wn = w & 1;
    const int lr = l & 15, lq = l >> 4;

    // XCD-aware remap (dispatch order: x fastest; assume XCD = flat % 8)
    const int gx = gridDim.x;
    int flat = blockIdx.y * gx + blockIdx.x;
    int per  = (gx * gridDim.y) >> 3;
    int flat2 = (flat & 7) * per + (flat >> 3);
    const int m0 = (flat2 / gx) * 128, n0 = (flat2 % gx) * 128;

    float4v acc[4][4];
#pragma unroll
    for (int mi = 0; mi < 4; mi++)
#pragma unroll
        for (int ni = 0; ni < 4; ni++) acc[mi][ni] = (float4v){0.f, 0.f, 0.f, 0.f};

    ushort8v rA0[2], rB0[2], rA1[2], rB1[2];   // two staging sets (even/odd k)

#define GLOAD(ra, rb, k0)                                                     \
    {                                                                          \
        _Pragma("unroll")                                                      \
        for (int i = 0; i < 2; i++) {                                          \
            int row = (w * 2 + i) * 16 + lr;                                   \
            ra[i] = *(const ushort8v*)(A  + (size_t)(m0 + row) * K + (k0) + lq * 8); \
            rb[i] = *(const ushort8v*)(Bm + (size_t)(n0 + row) * K + (k0) + lq * 8); \
        }                                                                      \
    }
#define SWRITE(buf, ra, rb)                                                    \
    {                                                                          \
        _Pragma("unroll")                                                      \
        for (int i = 0; i < 2; i++) {                                          \
            int rb8 = w * 2 + i;                                               \
            *(ushort8v*)&As[buf][rb8 * 512 + l * 8] = ra[i];                   \
            *(ushort8v*)&Bs[buf][rb8 * 512 + l * 8] = rb[i];                   \
        }                                                                      \
    }
#define COMPUTE(buf)                                                           \
    {                                                                          \
        short8 af[4], bfr[4];                                                  \
        _Pragma("unroll")                                                      \
        for (int mi = 0; mi < 4; mi++)                                         \
            af[mi] = *(const short8*)&As[buf][((wm * 4 + mi) * 64 + l) * 8];   \
        _Pragma("unroll")                                                      \
        for (int ni = 0; ni < 4; ni++)                                         \
            bfr[ni] = *(const short8*)&Bs[buf][((wn * 4 + ni) * 64 + l) * 8];  \
        _Pragma("unroll")                                                      \
        for (int mi = 0; mi < 4; mi++)                                         \
            _Pragma("unroll")                                                  \
            for (int ni = 0; ni < 4; ni++)                                     \
                acc[mi][ni] = __builtin_amdgcn_mfma_f32_16x16x32_bf16(         \
                    af[mi], bfr[ni], acc[mi][ni], 0, 0, 0);                    \
    }

    const int nk = K >> 5;                 // assumed even
    GLOAD(rA0, rB0, 0);
    SWRITE(0, rA0, rB0);                   // vmcnt dep wait here (prologue only)
    GLOAD(rA1, rB1, 32);                   // stays in flight across barrier
    __syncthreads();

    for (int kk = 0; kk < nk; kk += 2) {
        // k = kk (even): read buf0, prefetch kk+2 -> set0, write set1 -> buf1
        if (kk + 2 < nk) GLOAD(rA0, rB0, (kk + 2) << 5);
        COMPUTE(0);
        if (kk + 1 < nk) SWRITE(1, rA1, rB1);
        __syncthreads();
        // k = kk+1 (odd): read buf1, prefetch kk+3 -> set1, write set0 -> buf0
        if (kk + 1 < nk) {
            if (kk + 3 < nk) GLOAD(rA1, rB1, (kk + 3) << 5);
            COMPUTE(1);
            if (kk + 2 < nk) SWRITE(0, rA0, rB0);
            __syncthreads();
        }
    }
#undef GLOAD
#undef SWRITE
#undef COMPUTE

    const int q = l >> 4, c = l & 15;      // C/D: col=lane&15, row=quad*4+reg
#pragma unroll
    for (int mi = 0; mi < 4; mi++) {
        int row0 = m0 + wm * 64 + mi * 16 + q * 4;
#pragma unroll
        for (int ni = 0; ni < 4; ni++) {
            int col = n0 + wn * 64 + ni * 16 + c;
            float bv = bias ? bias[col] : 0.f;
#pragma unroll
            for (int r = 0; r < 4; r++) {
                float v = acc[mi][ni][r] + bv;
                if (BF16OUT) ((unsigned short*)Cout)[(size_t)(row0 + r) * N + col] = f2bf(v);
                else         ((float*)Cout)[(size_t)(row0 + r) * N + col] = v;
            }
        }
    }
}

// ---------------------------------------------------------------------------
// V transpose: qkvb V-cols -> vT[z][64][8192] bf16
// ---------------------------------------------------------------------------
__global__ __launch_bounds__(256) void vtrans(const unsigned short* __restrict__ qkvb,
                                              unsigned short* __restrict__ vT) {
    __shared__ unsigned short T[128][80];
    const int t = threadIdx.x;
    const int n0 = blockIdx.x * 128, z = blockIdx.y;
    const int b = z >> 3, h = z & 7;
#pragma unroll
    for (int i = 0; i < 4; i++) {
        int flat = t + i * 256;
        int n = flat >> 3, d8 = flat & 7;
        ushort8v v = *(const ushort8v*)(qkvb + ((size_t)b * NSEQ + n0 + n) * QKV_ + 1024 + h * 64 + d8 * 8);
        *(ushort8v*)&T[n][d8 * 8] = v;
    }
    __syncthreads();
#pragma unroll
    for (int i = 0; i < 4; i++) {
        int flat = t + i * 256;
        int d = flat >> 4, n8 = flat & 15;
        ushort8v o;
#pragma unroll
        for (int j = 0; j < 8; j++) o[j] = T[n8 * 8 + j][d];
        *(ushort8v*)(vT + ((size_t)z * 64 + d) * NSEQ + n0 + n8 * 8) = o;
    }
}

// ---------------------------------------------------------------------------
// Fused k' featuremap + split-K context via MFMA.
// ---------------------------------------------------------------------------
__global__ __launch_bounds__(256) void ctx_fused_mfma(
    const unsigned short* __restrict__ qkvb,
    const unsigned short* __restrict__ projb,
    const unsigned short* __restrict__ vT,
    float* __restrict__ partial)
{
    __shared__ __align__(16) unsigned short PB[32 * 512];
    __shared__ __align__(16) unsigned short KB[8 * 512];
    __shared__ __align__(16) unsigned short VB[8 * 512];
    __shared__ __align__(16) unsigned short KPA[32 * 512];
    const int t = threadIdx.x, w = t >> 6, l = t & 63;
    const int lr = l & 15, lq = l >> 4;
    const int s = blockIdx.x, z = blockIdx.y;
    const int b = z >> 3, h = z & 7;
    const int nchunk = s * 256;

    for (int idx = w; idx < 32; idx += 4) {
        int fblk = idx >> 1, kt = idx & 1;
        glds16(projb + (size_t)(fblk * 16 + lr) * 64 + kt * 32 + lq * 8, &PB[idx * 512]);
    }

    float4v acc[4][5];
#pragma unroll
    for (int mi = 0; mi < 4; mi++)
#pragma unroll
        for (int ni = 0; ni < 5; ni++) acc[mi][ni] = (float4v){0.f, 0.f, 0.f, 0.f};
    short ov = (lr == 0) ? (short)0x3F80 : (short)0;
    short8 ones = {ov, ov, ov, ov, ov, ov, ov, ov};

    for (int st = 0; st < 4; st++) {
        int nbase = nchunk + st * 64;
        __syncthreads();
        for (int idx = w; idx < 8; idx += 4) {
            int nblk = idx >> 1, kt = idx & 1;
            glds16(qkvb + ((size_t)b * NSEQ + nbase + nblk * 16 + lr) * QKV_ + 512 + h * 64 + kt * 32 + lq * 8,
                   &KB[idx * 512]);
        }
        for (int idx = w; idx < 8; idx += 4) {
            int dhb = idx >> 1, nt2 = idx & 1;
            glds16(vT + ((size_t)z * 64 + dhb * 16 + lr) * NSEQ + nbase + nt2 * 32 + lq * 8,
                   &VB[idx * 512]);
        }
        __syncthreads();

        float4v a2[4][4];
#pragma unroll
        for (int mi = 0; mi < 4; mi++)
#pragma unroll
            for (int ni = 0; ni < 4; ni++) a2[mi][ni] = (float4v){0.f, 0.f, 0.f, 0.f};
#pragma unroll
        for (int ks = 0; ks < 2; ks++) {
            short8 ka[4], pb[4];
#pragma unroll
            for (int mi = 0; mi < 4; mi++)
                ka[mi] = *(const short8*)&KB[((mi * 2 + ks) * 64 + l) * 8];
#pragma unroll
            for (int ni = 0; ni < 4; ni++)
                pb[ni] = *(const short8*)&PB[(((w * 4 + ni) * 2 + ks) * 64 + l) * 8];
#pragma unroll
            for (int mi = 0; mi < 4; mi++)
#pragma unroll
                for (int ni = 0; ni < 4; ni++)
                    a2[mi][ni] = __builtin_amdgcn_mfma_f32_16x16x32_bf16(ka[mi], pb[ni], a2[mi][ni], 0, 0, 0);
        }
#pragma unroll
        for (int mi = 0; mi < 4; mi++) {
            int nb = mi * 16 + lq * 4;
            int qoff = ((nb >> 3) & 3) * 256 + (nb & 7) * 2;
            int setn = nb >> 5;
#pragma unroll
            for (int ni = 0; ni < 4; ni++) {
                int f = w * 64 + ni * 16 + lr;
                float e0 = __expf(a2[mi][ni][0]);
                float e1 = __expf(a2[mi][ni][1]);
                float e2 = __expf(a2[mi][ni][2]);
                float e3 = __expf(a2[mi][ni][3]);
                uint2 p; p.x = pack2bf(e0, e1); p.y = pack2bf(e2, e3);
                *(uint2*)((char*)KPA + (size_t)(((f >> 4) * 2 + setn) * 1024 + qoff + (f & 15) * 16)) = p;
            }
        }
#pragma unroll
        for (int ks = 0; ks < 2; ks++) {
            short8 af[4], bf[4];
#pragma unroll
            for (int mi = 0; mi < 4; mi++)
                af[mi] = *(const short8*)&KPA[(((w * 4 + mi) * 2 + ks) * 64 + l) * 8];
#pragma unroll
            for (int ni = 0; ni < 4; ni++)
                bf[ni] = *(const short8*)&VB[((ni * 2 + ks) * 64 + l) * 8];
#pragma unroll
            for (int mi = 0; mi < 4; mi++) {
#pragma unroll
                for (int ni = 0; ni < 4; ni++)
                    acc[mi][ni] = __builtin_amdgcn_mfma_f32_16x16x32_bf16(af[mi], bf[ni], acc[mi][ni], 0, 0, 0);
                acc[mi][4] = __builtin_amdgcn_mfma_f32_16x16x32_bf16(af[mi], ones, acc[mi][4], 0, 0, 0);
            }
        }
    }
    float* base = partial + (size_t)(s * 16 + z) * 80 * 256;
#pragma unroll
    for (int mi = 0; mi < 4; mi++) {
        int f0r = w * 64 + mi * 16 + lq * 4;
#pragma unroll
        for (int ni = 0; ni < 5; ni++) {
            int col = ni * 16 + lr;
#pragma unroll
            for (int r = 0; r < 4; r++)
                base[(size_t)col * 256 + f0r + r] = acc[mi][ni][r];
        }
    }
}

// ---------------------------------------------------------------------------
__global__ __launch_bounds__(256) void ctx_reduce(const float* __restrict__ partial,
                                                  unsigned short* __restrict__ ctxT) {
    int idx = blockIdx.x * 256 + threadIdx.x;
    const int NC = 16 * 80 * 256;
    if (idx >= NC) return;
    float s = 0.f;
#pragma unroll
    for (int k = 0; k < 32; k++) s += partial[(size_t)k * NC + idx];
    ctxT[idx] = f2bf(s);
}

// ---------------------------------------------------------------------------
// Fused q' featuremap + (q'.ctx_ext) with D at col 64 -> bf16 attn out.
// ---------------------------------------------------------------------------
__global__ __launch_bounds__(256) void attn_fused_mfma(
    const unsigned short* __restrict__ qkvb,
    const unsigned short* __restrict__ projb,
    const unsigned short* __restrict__ ctxT,
    unsigned short* __restrict__ attnb)
{
    __shared__ __align__(16) unsigned short QB[16 * 512];
    __shared__ __align__(16) unsigned short PA[8 * 512];
    __shared__ __align__(16) unsigned short QPA[16 * 512];
    __shared__ __align__(16) unsigned short CB[10 * 512];
    const int t = threadIdx.x, w = t >> 6, l = t & 63;
    const int lr = l & 15, lq = l >> 4;
    const int m0 = blockIdx.x * 128, z = blockIdx.y;
    const int b = z >> 3, h = z & 7;

    for (int idx = w; idx < 16; idx += 4) {
        int mblk = idx >> 1, kt = idx & 1;
        glds16(qkvb + ((size_t)b * NSEQ + m0 + mblk * 16 + lr) * QKV_ + h * 64 + kt * 32 + lq * 8,
               &QB[idx * 512]);
    }
    float4v acc[2][5];
#pragma unroll
    for (int mi = 0; mi < 2; mi++)
#pragma unroll
        for (int ni = 0; ni < 5; ni++) acc[mi][ni] = (float4v){0.f, 0.f, 0.f, 0.f};

    for (int fs = 0; fs < 4; fs++) {
        int f0 = fs * 64;
        __syncthreads();
        for (int idx = w; idx < 8; idx += 4) {
            int fb = idx >> 1, kt = idx & 1;
            glds16(projb + (size_t)(f0 + fb * 16 + lr) * 64 + kt * 32 + lq * 8, &PA[idx * 512]);
        }
        for (int idx = w; idx < 10; idx += 4) {
            int dhb = idx >> 1, ft = idx & 1;
            glds16(ctxT + ((size_t)z * 80 + dhb * 16 + lr) * 256 + f0 + ft * 32 + lq * 8,
                   &CB[idx * 512]);
        }
        __syncthreads();

        float4v a2[4][2];
#pragma unroll
        for (int mi = 0; mi < 4; mi++)
#pragma unroll
            for (int ni = 0; ni < 2; ni++) a2[mi][ni] = (float4v){0.f, 0.f, 0.f, 0.f};
#pragma unroll
        for (int ks = 0; ks < 2; ks++) {
            short8 pa[4], qb[2];
#pragma unroll
            for (int mi = 0; mi < 4; mi++)
                pa[mi] = *(const short8*)&PA[((mi * 2 + ks) * 64 + l) * 8];
#pragma unroll
            for (int ni = 0; ni < 2; ni++)
                qb[ni] = *(const short8*)&QB[(((w * 2 + ni) * 2 + ks) * 64 + l) * 8];
#pragma unroll
            for (int mi = 0; mi < 4; mi++)
#pragma unroll
                for (int ni = 0; ni < 2; ni++)
                    a2[mi][ni] = __builtin_amdgcn_mfma_f32_16x16x32_bf16(pa[mi], qb[ni], a2[mi][ni], 0, 0, 0);
        }
#pragma unroll
        for (int mi = 0; mi < 4; mi++) {
            int fb2 = mi * 16 + lq * 4;
            int qoff = ((fb2 >> 3) & 3) * 256 + (fb2 & 7) * 2;
            int setf = fb2 >> 5;
#pragma unroll
            for (int ni = 0; ni < 2; ni++) {
                int m = w * 32 + ni * 16 + lr;
                float e0 = __expf(0.125f * a2[mi][ni][0]);
                float e1 = __expf(0.125f * a2[mi][ni][1]);
                float e2 = __expf(0.125f * a2[mi][ni][2]);
                float e3 = __expf(0.125f * a2[mi][ni][3]);
                uint2 p; p.x = pack2bf(e0, e1); p.y = pack2bf(e2, e3);
                *(uint2*)((char*)QPA + (size_t)(((m >> 4) * 2 + setf) * 1024 + qoff + (m & 15) * 16)) = p;
            }
        }
#pragma unroll
        for (int ks = 0; ks < 2; ks++) {
            short8 af[2], cb[5];
#pragma unroll
            for (int mi = 0; mi < 2; mi++)
                af[mi] = *(const short8*)&QPA[(((w * 2 + mi) * 2 + ks) * 64 + l) * 8];
#pragma unroll
            for (int ni = 0; ni < 5; ni++)
                cb[ni] = *(const short8*)&CB[((ni * 2 + ks) * 64 + l) * 8];
#pragma unroll
            for (int mi = 0; mi < 2; mi++)
#pragma unroll
                for (int ni = 0; ni < 5; ni++)
                    acc[mi][ni] = __builtin_amdgcn_mfma_f32_16x16x32_bf16(af[mi], cb[ni], acc[mi][ni], 0, 0, 0);
        }
    }
#pragma unroll
    for (int mi = 0; mi < 2; mi++) {
        int rowb = m0 + w * 32 + mi * 16 + lq * 4;
#pragma unroll
        for (int r = 0; r < 4; r++) {
            float dv = __shfl(acc[mi][4][r], (l & 48), 64);
            float rinv = 1.f / (dv + 1e-6f);
#pragma unroll
            for (int ni = 0; ni < 4; ni++)
                attnb[((size_t)b * NSEQ + rowb + r) * 512 + h * 64 + ni * 16 + lr] =
                    f2bf(acc[mi][ni][r] * rinv);
        }
    }
}

// ---------------------------------------------------------------------------
extern "C" void kernel_launch(void* const* d_in, const int* in_sizes, int n_in,
                              void* d_out, int out_size, void* d_ws, size_t ws_size,
                              hipStream_t stream) {
    const float* x    = (const float*)d_in[0];
    const float* Wqkv = (const float*)d_in[1];
    const float* Wout = (const float*)d_in[2];
    const float* bout = (const float*)d_in[3];
    const float* proj = (const float*)d_in[4];

    unsigned short* qkvb  = (unsigned short*)d_ws;                  // 25,165,824 u16
    unsigned short* vT    = qkvb + (size_t)M_ * QKV_;               // 8,388,608 u16
    float*          partial = (float*)(vT + (size_t)16 * 64 * NSEQ);// 10,485,760 f32
    unsigned short* ctxT  = (unsigned short*)(partial + (size_t)32 * 16 * 80 * 256); // 327,680 u16
    unsigned short* projb = ctxT + (size_t)16 * 80 * 256;           // 16,384 u16
    unsigned short* xb    = projb + 16384;                          // 8,388,608 u16
    unsigned short* attnb = xb;                                     // overlay (xb dead after gemm1)
    unsigned short* wqkvb = xb + (size_t)M_ * DIM_;                 // 786,432 u16
    unsigned short* woutb = wqkvb + (size_t)QKV_ * DIM_;            // 262,144 u16
    float* outp = (float*)d_out;                                    // total ws ~128.6 MB

    // 0) fp32 -> bf16 (single launch)
    cvt_all<<<dim3(4616), 256, 0, stream>>>(x, Wqkv, Wout, proj, xb, wqkvb, woutb, projb);
    // 1) qkv = x @ Wqkv^T  (bf16 out) — reg-prefetch pipeline + XCD swizzle
    gemm_nt_rp<true><<<dim3(QKV_ / 128, M_ / 128), 256, 0, stream>>>(xb, wqkvb, nullptr, qkvb, M_, QKV_, DIM_);
    // 2) V transpose
    vtrans<<<dim3(64, 16), 256, 0, stream>>>(qkvb, vT);
    // 3) fused k' + context partials (MFMA)
    ctx_fused_mfma<<<dim3(32, 16), 256, 0, stream>>>(qkvb, projb, vT, partial);
    // 4) reduce -> ctxT bf16 (incl. ksum row)
    ctx_reduce<<<dim3(1280), 256, 0, stream>>>(partial, ctxT);
    // 5) fused q' + attention out (MFMA), bf16
    attn_fused_mfma<<<dim3(64, 16), 256, 0, stream>>>(qkvb, projb, ctxT, attnb);
    // 6) out = attn @ Wout^T + bout — reg-prefetch pipeline
    gemm_nt_rp<false><<<dim3(DIM_ / 128, M_ / 128), 256, 0, stream>>>(attnb, woutb, bout, outp, M_, DIM_, DIM_);
}

// Round 7
// 224.627 us; speedup vs baseline: 1.0431x; 1.0431x over previous
//
#include <hip/hip_runtime.h>
#include <math.h>

#define B_    2
#define NSEQ  8192
#define DIM_  512
#define H_    8
#define DH_   64
#define F_    256
#define M_    (B_*NSEQ)      // 16384
#define QKV_  1536

typedef __attribute__((ext_vector_type(8))) short     short8;
typedef __attribute__((ext_vector_type(4))) float     float4v;
typedef __attribute__((ext_vector_type(8))) unsigned short ushort8v;

__device__ __forceinline__ unsigned short f2bf(float f) {
    unsigned u = __float_as_uint(f);
    u += 0x7FFFu + ((u >> 16) & 1u);   // RNE
    return (unsigned short)(u >> 16);
}
__device__ __forceinline__ float bf2f(unsigned short h) {
    unsigned u = ((unsigned)h) << 16;
    return __uint_as_float(u);
}
// pack two floats -> two bf16 (truncate; bias cancels in N/D ratio)
__device__ __forceinline__ unsigned pack2bf(float lo, float hi) {
    return __builtin_amdgcn_perm(__float_as_uint(hi), __float_as_uint(lo), 0x07060302);
}
__device__ __forceinline__ void glds16(const void* g, void* s) {
    __builtin_amdgcn_global_load_lds(
        (const __attribute__((address_space(1))) unsigned int*)g,
        (__attribute__((address_space(3))) unsigned int*)s, 16, 0, 0);
}

// ---------------------------------------------------------------------------
// fused fp32->bf16 for all 4 inputs, one launch.
// ---------------------------------------------------------------------------
__global__ __launch_bounds__(256) void cvt_all(const float* __restrict__ x,
                                               const float* __restrict__ wqkv,
                                               const float* __restrict__ wout,
                                               const float* __restrict__ proj,
                                               unsigned short* __restrict__ xb,
                                               unsigned short* __restrict__ wqkvb,
                                               unsigned short* __restrict__ woutb,
                                               unsigned short* __restrict__ projb) {
    int bid = blockIdx.x;
    const float* in; unsigned short* out; int i;
    if (bid < 4096)      { in = x;    out = xb;    i = bid * 256 + threadIdx.x; }
    else if (bid < 4480) { in = wqkv; out = wqkvb; i = (bid - 4096) * 256 + threadIdx.x; }
    else if (bid < 4608) { in = wout; out = woutb; i = (bid - 4480) * 256 + threadIdx.x; }
    else                 { in = proj; out = projb; i = (bid - 4608) * 256 + threadIdx.x; }
    float4 a = ((const float4*)in)[2 * i];
    float4 b = ((const float4*)in)[2 * i + 1];
    ushort8v o;
    o[0] = f2bf(a.x); o[1] = f2bf(a.y); o[2] = f2bf(a.z); o[3] = f2bf(a.w);
    o[4] = f2bf(b.x); o[5] = f2bf(b.y); o[6] = f2bf(b.z); o[7] = f2bf(b.w);
    ((ushort8v*)out)[i] = o;
}

// ---------------------------------------------------------------------------
// Ping-pong glds NT GEMM (round-5 structure, best measured) + XCD swizzle
// (round-6's verified 3x FETCH reduction). 128x128, BK=32, 1 barrier/iter.
// ---------------------------------------------------------------------------
template<bool BF16OUT>
__global__ __launch_bounds__(256) void gemm_nt_pp(const unsigned short* __restrict__ A,
                                                  const unsigned short* __restrict__ Bm,
                                                  const float* __restrict__ bias,
                                                  void* __restrict__ Cout,
                                                  int M, int N, int K) {
    __shared__ __align__(16) unsigned short As[2][128 * 32];
    __shared__ __align__(16) unsigned short Bs[2][128 * 32];
    const int t  = threadIdx.x;
    const int w  = t >> 6, l = t & 63;
    const int wm = w >> 1, wn = w & 1;
    const int lr = l & 15, lq = l >> 4;

    // XCD-aware remap: contiguous tile range per XCD (flat % 8 = XCD)
    const int gx = gridDim.x;
    int flat = blockIdx.y * gx + blockIdx.x;
    int per  = (gx * gridDim.y) >> 3;
    int flat2 = (flat & 7) * per + (flat >> 3);
    const int m0 = (flat2 / gx) * 128, n0 = (flat2 % gx) * 128;

    float4v acc[4][4];
#pragma unroll
    for (int mi = 0; mi < 4; mi++)
#pragma unroll
        for (int ni = 0; ni < 4; ni++) acc[mi][ni] = (float4v){0.f, 0.f, 0.f, 0.f};

    auto stage = [&](int buf, int k0) {
#pragma unroll
        for (int i = 0; i < 2; i++) {
            int rb8 = w * 2 + i;
            int row = rb8 * 16 + lr;
            glds16(A + (size_t)(m0 + row) * K + k0 + lq * 8, &As[buf][rb8 * 512]);
            glds16(Bm + (size_t)(n0 + row) * K + k0 + lq * 8, &Bs[buf][rb8 * 512]);
        }
    };

    const int nk = K >> 5;
    stage(0, 0);
    __syncthreads();

    for (int k = 0; k < nk; k++) {
        const int cur = k & 1;
        if (k + 1 < nk) stage(cur ^ 1, (k + 1) << 5);

        short8 af[4], bfr[4];
#pragma unroll
        for (int mi = 0; mi < 4; mi++)
            af[mi] = *(const short8*)&As[cur][((wm * 4 + mi) * 64 + l) * 8];
#pragma unroll
        for (int ni = 0; ni < 4; ni++)
            bfr[ni] = *(const short8*)&Bs[cur][((wn * 4 + ni) * 64 + l) * 8];
#pragma unroll
        for (int mi = 0; mi < 4; mi++)
#pragma unroll
            for (int ni = 0; ni < 4; ni++)
                acc[mi][ni] = __builtin_amdgcn_mfma_f32_16x16x32_bf16(
                    af[mi], bfr[ni], acc[mi][ni], 0, 0, 0);

        if (k + 1 < nk) __syncthreads();
    }

    const int q = l >> 4, c = l & 15;
#pragma unroll
    for (int mi = 0; mi < 4; mi++) {
        int row0 = m0 + wm * 64 + mi * 16 + q * 4;
#pragma unroll
        for (int ni = 0; ni < 4; ni++) {
            int col = n0 + wn * 64 + ni * 16 + c;
            float bv = bias ? bias[col] : 0.f;
#pragma unroll
            for (int r = 0; r < 4; r++) {
                float v = acc[mi][ni][r] + bv;
                if (BF16OUT) ((unsigned short*)Cout)[(size_t)(row0 + r) * N + col] = f2bf(v);
                else         ((float*)Cout)[(size_t)(row0 + r) * N + col] = v;
            }
        }
    }
}

// ---------------------------------------------------------------------------
// V transpose: qkvb V-cols -> vT[z][64][8192] bf16
// ---------------------------------------------------------------------------
__global__ __launch_bounds__(256) void vtrans(const unsigned short* __restrict__ qkvb,
                                              unsigned short* __restrict__ vT) {
    __shared__ unsigned short T[128][80];
    const int t = threadIdx.x;
    const int n0 = blockIdx.x * 128, z = blockIdx.y;
    const int b = z >> 3, h = z & 7;
#pragma unroll
    for (int i = 0; i < 4; i++) {
        int flat = t + i * 256;
        int n = flat >> 3, d8 = flat & 7;
        ushort8v v = *(const ushort8v*)(qkvb + ((size_t)b * NSEQ + n0 + n) * QKV_ + 1024 + h * 64 + d8 * 8);
        *(ushort8v*)&T[n][d8 * 8] = v;
    }
    __syncthreads();
#pragma unroll
    for (int i = 0; i < 4; i++) {
        int flat = t + i * 256;
        int d = flat >> 4, n8 = flat & 15;
        ushort8v o;
#pragma unroll
        for (int j = 0; j < 8; j++) o[j] = T[n8 * 8 + j][d];
        *(ushort8v*)(vT + ((size_t)z * 64 + d) * NSEQ + n0 + n8 * 8) = o;
    }
}

// ---------------------------------------------------------------------------
// Fused k' featuremap + split-K context via MFMA. f-split x2: each block
// covers 128 f -> LDS 48 KB (PB16+KPA16+KB8+VB8) -> 3 blocks/CU (was 80 KB,
// 2/CU). grid (32 s, 2 fh, 16 z). Partials stored bf16 (halved traffic).
// ---------------------------------------------------------------------------
__global__ __launch_bounds__(256) void ctx_fused_mfma(
    const unsigned short* __restrict__ qkvb,
    const unsigned short* __restrict__ projb,
    const unsigned short* __restrict__ vT,
    unsigned short* __restrict__ partial)   // [32 s][16 z][80][256] bf16
{
    __shared__ __align__(16) unsigned short PB[16 * 512];   // proj B-frags (f-half, resident)
    __shared__ __align__(16) unsigned short KB[8 * 512];    // K-rows A-frags (per step)
    __shared__ __align__(16) unsigned short VB[8 * 512];    // vT B-frags (per step)
    __shared__ __align__(16) unsigned short KPA[16 * 512];  // kp A-frags (f-half)
    const int t = threadIdx.x, w = t >> 6, l = t & 63;
    const int lr = l & 15, lq = l >> 4;
    const int s = blockIdx.x, fh = blockIdx.y, z = blockIdx.z;
    const int b = z >> 3, h = z & 7;
    const int nchunk = s * 256;

    for (int idx = w; idx < 16; idx += 4) {
        int fblk = idx >> 1, kt = idx & 1;
        glds16(projb + (size_t)(fh * 128 + fblk * 16 + lr) * 64 + kt * 32 + lq * 8, &PB[idx * 512]);
    }

    float4v acc[2][5];
#pragma unroll
    for (int mi = 0; mi < 2; mi++)
#pragma unroll
        for (int ni = 0; ni < 5; ni++) acc[mi][ni] = (float4v){0.f, 0.f, 0.f, 0.f};
    short ov = (lr == 0) ? (short)0x3F80 : (short)0;
    short8 ones = {ov, ov, ov, ov, ov, ov, ov, ov};

    for (int st = 0; st < 4; st++) {
        int nbase = nchunk + st * 64;
        __syncthreads();
        for (int idx = w; idx < 8; idx += 4) {
            int nblk = idx >> 1, kt = idx & 1;
            glds16(qkvb + ((size_t)b * NSEQ + nbase + nblk * 16 + lr) * QKV_ + 512 + h * 64 + kt * 32 + lq * 8,
                   &KB[idx * 512]);
        }
        for (int idx = w; idx < 8; idx += 4) {
            int dhb = idx >> 1, nt2 = idx & 1;
            glds16(vT + ((size_t)z * 64 + dhb * 16 + lr) * NSEQ + nbase + nt2 * 32 + lq * 8,
                   &VB[idx * 512]);
        }
        __syncthreads();

        // phase A: rows n (mi 0..3), cols f' (wave w: 32 f, ni 0..1)
        float4v a2[4][2];
#pragma unroll
        for (int mi = 0; mi < 4; mi++)
#pragma unroll
            for (int ni = 0; ni < 2; ni++) a2[mi][ni] = (float4v){0.f, 0.f, 0.f, 0.f};
#pragma unroll
        for (int ks = 0; ks < 2; ks++) {
            short8 ka[4], pb[2];
#pragma unroll
            for (int mi = 0; mi < 4; mi++)
                ka[mi] = *(const short8*)&KB[((mi * 2 + ks) * 64 + l) * 8];
#pragma unroll
            for (int ni = 0; ni < 2; ni++)
                pb[ni] = *(const short8*)&PB[(((w * 2 + ni) * 2 + ks) * 64 + l) * 8];
#pragma unroll
            for (int mi = 0; mi < 4; mi++)
#pragma unroll
                for (int ni = 0; ni < 2; ni++)
                    a2[mi][ni] = __builtin_amdgcn_mfma_f32_16x16x32_bf16(ka[mi], pb[ni], a2[mi][ni], 0, 0, 0);
        }
        // exp -> bf16 -> KPA (A-frag order, local f' = w*32 + ni*16 + lr)
#pragma unroll
        for (int mi = 0; mi < 4; mi++) {
            int nb = mi * 16 + lq * 4;
            int qoff = ((nb >> 3) & 3) * 256 + (nb & 7) * 2;
            int setn = nb >> 5;
#pragma unroll
            for (int ni = 0; ni < 2; ni++) {
                int fp = w * 32 + ni * 16 + lr;
                float e0 = __expf(a2[mi][ni][0]);
                float e1 = __expf(a2[mi][ni][1]);
                float e2 = __expf(a2[mi][ni][2]);
                float e3 = __expf(a2[mi][ni][3]);
                uint2 p; p.x = pack2bf(e0, e1); p.y = pack2bf(e2, e3);
                *(uint2*)((char*)KPA + (size_t)(((fp >> 4) * 2 + setn) * 1024 + qoff + (fp & 15) * 16)) = p;
            }
        }
        // phase B: rows f' (wave w: mi 0..1), cols dh_ext (ni; ni=4 -> ksum)
#pragma unroll
        for (int ks = 0; ks < 2; ks++) {
            short8 af[2], bf[4];
#pragma unroll
            for (int mi = 0; mi < 2; mi++)
                af[mi] = *(const short8*)&KPA[(((w * 2 + mi) * 2 + ks) * 64 + l) * 8];
#pragma unroll
            for (int ni = 0; ni < 4; ni++)
                bf[ni] = *(const short8*)&VB[((ni * 2 + ks) * 64 + l) * 8];
#pragma unroll
            for (int mi = 0; mi < 2; mi++) {
#pragma unroll
                for (int ni = 0; ni < 4; ni++)
                    acc[mi][ni] = __builtin_amdgcn_mfma_f32_16x16x32_bf16(af[mi], bf[ni], acc[mi][ni], 0, 0, 0);
                acc[mi][4] = __builtin_amdgcn_mfma_f32_16x16x32_bf16(af[mi], ones, acc[mi][4], 0, 0, 0);
            }
        }
    }
    unsigned short* base = partial + (size_t)(s * 16 + z) * 80 * 256 + fh * 128;
#pragma unroll
    for (int mi = 0; mi < 2; mi++) {
        int f0r = w * 32 + mi * 16 + lq * 4;
#pragma unroll
        for (int ni = 0; ni < 5; ni++) {
            int col = ni * 16 + lr;
#pragma unroll
            for (int r = 0; r < 4; r++)
                base[(size_t)col * 256 + f0r + r] = f2bf(acc[mi][ni][r]);
        }
    }
}

// ---------------------------------------------------------------------------
// Reduce split-K bf16 partials -> ctxT bf16 [z][80][256] (row 64 = ksum).
// Vectorized: each thread sums 8 contiguous f over 32 splits.
// ---------------------------------------------------------------------------
__global__ __launch_bounds__(256) void ctx_reduce(const unsigned short* __restrict__ partial,
                                                  unsigned short* __restrict__ ctxT) {
    int idx8 = blockIdx.x * 256 + threadIdx.x;   // 0 .. 40959
    const int INNER = 16 * 80 * 256;             // per-split extent
    size_t off = (size_t)idx8 * 8;
    float s0 = 0.f, s1 = 0.f, s2 = 0.f, s3 = 0.f, s4 = 0.f, s5 = 0.f, s6 = 0.f, s7 = 0.f;
#pragma unroll
    for (int k = 0; k < 32; k++) {
        ushort8v v = *(const ushort8v*)(partial + (size_t)k * INNER + off);
        s0 += bf2f(v[0]); s1 += bf2f(v[1]); s2 += bf2f(v[2]); s3 += bf2f(v[3]);
        s4 += bf2f(v[4]); s5 += bf2f(v[5]); s6 += bf2f(v[6]); s7 += bf2f(v[7]);
    }
    ushort8v o;
    o[0] = f2bf(s0); o[1] = f2bf(s1); o[2] = f2bf(s2); o[3] = f2bf(s3);
    o[4] = f2bf(s4); o[5] = f2bf(s5); o[6] = f2bf(s6); o[7] = f2bf(s7);
    *(ushort8v*)(ctxT + off) = o;
}

// ---------------------------------------------------------------------------
// Fused q' featuremap + (q'.ctx_ext) with D at col 64 -> bf16 attn out.
// ---------------------------------------------------------------------------
__global__ __launch_bounds__(256) void attn_fused_mfma(
    const unsigned short* __restrict__ qkvb,
    const unsigned short* __restrict__ projb,
    const unsigned short* __restrict__ ctxT,
    unsigned short* __restrict__ attnb)
{
    __shared__ __align__(16) unsigned short QB[16 * 512];
    __shared__ __align__(16) unsigned short PA[8 * 512];
    __shared__ __align__(16) unsigned short QPA[16 * 512];
    __shared__ __align__(16) unsigned short CB[10 * 512];
    const int t = threadIdx.x, w = t >> 6, l = t & 63;
    const int lr = l & 15, lq = l >> 4;
    const int m0 = blockIdx.x * 128, z = blockIdx.y;
    const int b = z >> 3, h = z & 7;

    for (int idx = w; idx < 16; idx += 4) {
        int mblk = idx >> 1, kt = idx & 1;
        glds16(qkvb + ((size_t)b * NSEQ + m0 + mblk * 16 + lr) * QKV_ + h * 64 + kt * 32 + lq * 8,
               &QB[idx * 512]);
    }
    float4v acc[2][5];
#pragma unroll
    for (int mi = 0; mi < 2; mi++)
#pragma unroll
        for (int ni = 0; ni < 5; ni++) acc[mi][ni] = (float4v){0.f, 0.f, 0.f, 0.f};

    for (int fs = 0; fs < 4; fs++) {
        int f0 = fs * 64;
        __syncthreads();
        for (int idx = w; idx < 8; idx += 4) {
            int fb = idx >> 1, kt = idx & 1;
            glds16(projb + (size_t)(f0 + fb * 16 + lr) * 64 + kt * 32 + lq * 8, &PA[idx * 512]);
        }
        for (int idx = w; idx < 10; idx += 4) {
            int dhb = idx >> 1, ft = idx & 1;
            glds16(ctxT + ((size_t)z * 80 + dhb * 16 + lr) * 256 + f0 + ft * 32 + lq * 8,
                   &CB[idx * 512]);
        }
        __syncthreads();

        float4v a2[4][2];
#pragma unroll
        for (int mi = 0; mi < 4; mi++)
#pragma unroll
            for (int ni = 0; ni < 2; ni++) a2[mi][ni] = (float4v){0.f, 0.f, 0.f, 0.f};
#pragma unroll
        for (int ks = 0; ks < 2; ks++) {
            short8 pa[4], qb[2];
#pragma unroll
            for (int mi = 0; mi < 4; mi++)
                pa[mi] = *(const short8*)&PA[((mi * 2 + ks) * 64 + l) * 8];
#pragma unroll
            for (int ni = 0; ni < 2; ni++)
                qb[ni] = *(const short8*)&QB[(((w * 2 + ni) * 2 + ks) * 64 + l) * 8];
#pragma unroll
            for (int mi = 0; mi < 4; mi++)
#pragma unroll
                for (int ni = 0; ni < 2; ni++)
                    a2[mi][ni] = __builtin_amdgcn_mfma_f32_16x16x32_bf16(pa[mi], qb[ni], a2[mi][ni], 0, 0, 0);
        }
#pragma unroll
        for (int mi = 0; mi < 4; mi++) {
            int fb2 = mi * 16 + lq * 4;
            int qoff = ((fb2 >> 3) & 3) * 256 + (fb2 & 7) * 2;
            int setf = fb2 >> 5;
#pragma unroll
            for (int ni = 0; ni < 2; ni++) {
                int m = w * 32 + ni * 16 + lr;
                float e0 = __expf(0.125f * a2[mi][ni][0]);
                float e1 = __expf(0.125f * a2[mi][ni][1]);
                float e2 = __expf(0.125f * a2[mi][ni][2]);
                float e3 = __expf(0.125f * a2[mi][ni][3]);
                uint2 p; p.x = pack2bf(e0, e1); p.y = pack2bf(e2, e3);
                *(uint2*)((char*)QPA + (size_t)(((m >> 4) * 2 + setf) * 1024 + qoff + (m & 15) * 16)) = p;
            }
        }
#pragma unroll
        for (int ks = 0; ks < 2; ks++) {
            short8 af[2], cb[5];
#pragma unroll
            for (int mi = 0; mi < 2; mi++)
                af[mi] = *(const short8*)&QPA[(((w * 2 + mi) * 2 + ks) * 64 + l) * 8];
#pragma unroll
            for (int ni = 0; ni < 5; ni++)
                cb[ni] = *(const short8*)&CB[((ni * 2 + ks) * 64 + l) * 8];
#pragma unroll
            for (int mi = 0; mi < 2; mi++)
#pragma unroll
                for (int ni = 0; ni < 5; ni++)
                    acc[mi][ni] = __builtin_amdgcn_mfma_f32_16x16x32_bf16(af[mi], cb[ni], acc[mi][ni], 0, 0, 0);
        }
    }
#pragma unroll
    for (int mi = 0; mi < 2; mi++) {
        int rowb = m0 + w * 32 + mi * 16 + lq * 4;
#pragma unroll
        for (int r = 0; r < 4; r++) {
            float dv = __shfl(acc[mi][4][r], (l & 48), 64);
            float rinv = 1.f / (dv + 1e-6f);
#pragma unroll
            for (int ni = 0; ni < 4; ni++)
                attnb[((size_t)b * NSEQ + rowb + r) * 512 + h * 64 + ni * 16 + lr] =
                    f2bf(acc[mi][ni][r] * rinv);
        }
    }
}

// ---------------------------------------------------------------------------
extern "C" void kernel_launch(void* const* d_in, const int* in_sizes, int n_in,
                              void* d_out, int out_size, void* d_ws, size_t ws_size,
                              hipStream_t stream) {
    const float* x    = (const float*)d_in[0];
    const float* Wqkv = (const float*)d_in[1];
    const float* Wout = (const float*)d_in[2];
    const float* bout = (const float*)d_in[3];
    const float* proj = (const float*)d_in[4];

    unsigned short* qkvb    = (unsigned short*)d_ws;                 // 25,165,824 u16
    unsigned short* vT      = qkvb + (size_t)M_ * QKV_;              // 8,388,608 u16
    unsigned short* partial = vT + (size_t)16 * 64 * NSEQ;           // 10,485,760 u16 (bf16)
    unsigned short* ctxT    = partial + (size_t)32 * 16 * 80 * 256;  // 327,680 u16
    unsigned short* projb   = ctxT + (size_t)16 * 80 * 256;          // 16,384 u16
    unsigned short* xb      = projb + 16384;                         // 8,388,608 u16
    unsigned short* attnb   = xb;                                    // overlay (xb dead after gemm1)
    unsigned short* wqkvb   = xb + (size_t)M_ * DIM_;                // 786,432 u16
    unsigned short* woutb   = wqkvb + (size_t)QKV_ * DIM_;           // 262,144 u16
    float* outp = (float*)d_out;                                     // total ws ~108 MB

    // 0) fp32 -> bf16 (single launch)
    cvt_all<<<dim3(4616), 256, 0, stream>>>(x, Wqkv, Wout, proj, xb, wqkvb, woutb, projb);
    // 1) qkv = x @ Wqkv^T  (bf16 out) — ping-pong + XCD swizzle
    gemm_nt_pp<true><<<dim3(QKV_ / 128, M_ / 128), 256, 0, stream>>>(xb, wqkvb, nullptr, qkvb, M_, QKV_, DIM_);
    // 2) V transpose
    vtrans<<<dim3(64, 16), 256, 0, stream>>>(qkvb, vT);
    // 3) fused k' + context partials (MFMA, f-split x2, bf16 partials)
    ctx_fused_mfma<<<dim3(32, 2, 16), 256, 0, stream>>>(qkvb, projb, vT, partial);
    // 4) reduce -> ctxT bf16 (incl. ksum row), vectorized
    ctx_reduce<<<dim3(160), 256, 0, stream>>>(partial, ctxT);
    // 5) fused q' + attention out (MFMA), bf16
    attn_fused_mfma<<<dim3(64, 16), 256, 0, stream>>>(qkvb, projb, ctxT, attnb);
    // 6) out = attn @ Wout^T + bout — ping-pong + XCD swizzle
    gemm_nt_pp<false><<<dim3(DIM_ / 128, M_ / 128), 256, 0, stream>>>(attnb, woutb, bout, outp, M_, DIM_, DIM_);
}

// Round 9
// 212.679 us; speedup vs baseline: 1.1017x; 1.0562x over previous
//
#include <hip/hip_runtime.h>
#include <math.h>

#define B_    2
#define NSEQ  8192
#define DIM_  512
#define H_    8
#define DH_   64
#define F_    256
#define M_    (B_*NSEQ)      // 16384
#define QKV_  1536

typedef __attribute__((ext_vector_type(8))) short     short8;
typedef __attribute__((ext_vector_type(4))) float     float4v;
typedef __attribute__((ext_vector_type(8))) unsigned short ushort8v;

__device__ __forceinline__ unsigned short f2bf(float f) {
    unsigned u = __float_as_uint(f);
    u += 0x7FFFu + ((u >> 16) & 1u);   // RNE
    return (unsigned short)(u >> 16);
}
__device__ __forceinline__ float bf2f(unsigned short h) {
    unsigned u = ((unsigned)h) << 16;
    return __uint_as_float(u);
}
// pack two floats -> two bf16 (truncate; bias cancels in N/D ratio)
__device__ __forceinline__ unsigned pack2bf(float lo, float hi) {
    return __builtin_amdgcn_perm(__float_as_uint(hi), __float_as_uint(lo), 0x07060302);
}
__device__ __forceinline__ void glds16(const void* g, void* s) {
    __builtin_amdgcn_global_load_lds(
        (const __attribute__((address_space(1))) unsigned int*)g,
        (__attribute__((address_space(3))) unsigned int*)s, 16, 0, 0);
}

// ---------------------------------------------------------------------------
// fused fp32->bf16 for all 4 inputs, one launch.
// ---------------------------------------------------------------------------
__global__ __launch_bounds__(256) void cvt_all(const float* __restrict__ x,
                                               const float* __restrict__ wqkv,
                                               const float* __restrict__ wout,
                                               const float* __restrict__ proj,
                                               unsigned short* __restrict__ xb,
                                               unsigned short* __restrict__ wqkvb,
                                               unsigned short* __restrict__ woutb,
                                               unsigned short* __restrict__ projb) {
    int bid = blockIdx.x;
    const float* in; unsigned short* out; int i;
    if (bid < 4096)      { in = x;    out = xb;    i = bid * 256 + threadIdx.x; }
    else if (bid < 4480) { in = wqkv; out = wqkvb; i = (bid - 4096) * 256 + threadIdx.x; }
    else if (bid < 4608) { in = wout; out = woutb; i = (bid - 4480) * 256 + threadIdx.x; }
    else                 { in = proj; out = projb; i = (bid - 4608) * 256 + threadIdx.x; }
    float4 a = ((const float4*)in)[2 * i];
    float4 b = ((const float4*)in)[2 * i + 1];
    ushort8v o;
    o[0] = f2bf(a.x); o[1] = f2bf(a.y); o[2] = f2bf(a.z); o[3] = f2bf(a.w);
    o[4] = f2bf(b.x); o[5] = f2bf(b.y); o[6] = f2bf(b.z); o[7] = f2bf(b.w);
    ((ushort8v*)out)[i] = o;
}

// ---------------------------------------------------------------------------
// Ping-pong glds NT GEMM + XCD swizzle. NEW: optional vTout — for qkv GEMM,
// V-columns (col>=1024) are written TRANSPOSED into vT[z][64][8192] instead
// of qkvb (V region of qkvb is only ever consumed via vT). Kills the vtrans
// kernel and 33 MB write + 33 MB read.
// ---------------------------------------------------------------------------
template<bool BF16OUT>
__global__ __launch_bounds__(256) void gemm_nt_pp(const unsigned short* __restrict__ A,
                                                  const unsigned short* __restrict__ Bm,
                                                  const float* __restrict__ bias,
                                                  void* __restrict__ Cout,
                                                  unsigned short* __restrict__ vTout,
                                                  int M, int N, int K) {
    __shared__ __align__(16) unsigned short As[2][128 * 32];
    __shared__ __align__(16) unsigned short Bs[2][128 * 32];
    const int t  = threadIdx.x;
    const int w  = t >> 6, l = t & 63;
    const int wm = w >> 1, wn = w & 1;
    const int lr = l & 15, lq = l >> 4;

    // XCD-aware remap: contiguous tile range per XCD (flat % 8 = XCD)
    const int gx = gridDim.x;
    int flat = blockIdx.y * gx + blockIdx.x;
    int per  = (gx * gridDim.y) >> 3;
    int flat2 = (flat & 7) * per + (flat >> 3);
    const int m0 = (flat2 / gx) * 128, n0 = (flat2 % gx) * 128;

    float4v acc[4][4];
#pragma unroll
    for (int mi = 0; mi < 4; mi++)
#pragma unroll
        for (int ni = 0; ni < 4; ni++) acc[mi][ni] = (float4v){0.f, 0.f, 0.f, 0.f};

    auto stage = [&](int buf, int k0) {
#pragma unroll
        for (int i = 0; i < 2; i++) {
            int rb8 = w * 2 + i;
            int row = rb8 * 16 + lr;
            glds16(A + (size_t)(m0 + row) * K + k0 + lq * 8, &As[buf][rb8 * 512]);
            glds16(Bm + (size_t)(n0 + row) * K + k0 + lq * 8, &Bs[buf][rb8 * 512]);
        }
    };

    const int nk = K >> 5;
    stage(0, 0);
    __syncthreads();

    for (int k = 0; k < nk; k++) {
        const int cur = k & 1;
        if (k + 1 < nk) stage(cur ^ 1, (k + 1) << 5);

        short8 af[4], bfr[4];
#pragma unroll
        for (int mi = 0; mi < 4; mi++)
            af[mi] = *(const short8*)&As[cur][((wm * 4 + mi) * 64 + l) * 8];
#pragma unroll
        for (int ni = 0; ni < 4; ni++)
            bfr[ni] = *(const short8*)&Bs[cur][((wn * 4 + ni) * 64 + l) * 8];
#pragma unroll
        for (int mi = 0; mi < 4; mi++)
#pragma unroll
            for (int ni = 0; ni < 4; ni++)
                acc[mi][ni] = __builtin_amdgcn_mfma_f32_16x16x32_bf16(
                    af[mi], bfr[ni], acc[mi][ni], 0, 0, 0);

        if (k + 1 < nk) __syncthreads();
    }

    const int q = l >> 4, c = l & 15;      // C/D: col=lane&15, row=quad*4+reg
#pragma unroll
    for (int mi = 0; mi < 4; mi++) {
        int row0 = m0 + wm * 64 + mi * 16 + q * 4;
#pragma unroll
        for (int ni = 0; ni < 4; ni++) {
            int col = n0 + wn * 64 + ni * 16 + c;
            if (BF16OUT && vTout != nullptr && col >= 1024) {
                // V path: write transposed into vT[z=b*8+h][dh][seq]
                int cm = col - 1024;
                int h2 = cm >> 6, dh = cm & 63;
                int bq = row0 >> 13;
                size_t nn = (size_t)(row0 & 8191);
                unsigned short* dst = vTout + (((size_t)bq * 8 + h2) * 64 + dh) * NSEQ + nn;
                uint2 pv;
                pv.x = ((unsigned)f2bf(acc[mi][ni][1]) << 16) | f2bf(acc[mi][ni][0]);
                pv.y = ((unsigned)f2bf(acc[mi][ni][3]) << 16) | f2bf(acc[mi][ni][2]);
                *(uint2*)dst = pv;
            } else {
                float bv = bias ? bias[col] : 0.f;
#pragma unroll
                for (int r = 0; r < 4; r++) {
                    float v = acc[mi][ni][r] + bv;
                    if (BF16OUT) ((unsigned short*)Cout)[(size_t)(row0 + r) * N + col] = f2bf(v);
                    else         ((float*)Cout)[(size_t)(row0 + r) * N + col] = v;
                }
            }
        }
    }
}

// ---------------------------------------------------------------------------
// Fused k' featuremap + split-K context via MFMA (round-7 verified version).
// Changed only: split count 32 -> 16 (8 n-steps of 64 per block).
// grid (16 s, 2 fh, 16 z); LDS 48 KB -> 3 blocks/CU.
// ---------------------------------------------------------------------------
__global__ __launch_bounds__(256) void ctx_fused_mfma(
    const unsigned short* __restrict__ qkvb,
    const unsigned short* __restrict__ projb,
    const unsigned short* __restrict__ vT,
    unsigned short* __restrict__ partial)   // [16 s][16 z][80][256] bf16
{
    __shared__ __align__(16) unsigned short PB[16 * 512];   // proj B-frags (f-half, resident)
    __shared__ __align__(16) unsigned short KB[8 * 512];    // K-rows A-frags (per step)
    __shared__ __align__(16) unsigned short VB[8 * 512];    // vT B-frags (per step)
    __shared__ __align__(16) unsigned short KPA[16 * 512];  // kp A-frags (f-half)
    const int t = threadIdx.x, w = t >> 6, l = t & 63;
    const int lr = l & 15, lq = l >> 4;
    const int s = blockIdx.x, fh = blockIdx.y, z = blockIdx.z;
    const int b = z >> 3, h = z & 7;
    const int nchunk = s * 512;

    for (int idx = w; idx < 16; idx += 4) {
        int fblk = idx >> 1, kt = idx & 1;
        glds16(projb + (size_t)(fh * 128 + fblk * 16 + lr) * 64 + kt * 32 + lq * 8, &PB[idx * 512]);
    }

    float4v acc[2][5];
#pragma unroll
    for (int mi = 0; mi < 2; mi++)
#pragma unroll
        for (int ni = 0; ni < 5; ni++) acc[mi][ni] = (float4v){0.f, 0.f, 0.f, 0.f};
    short ov = (lr == 0) ? (short)0x3F80 : (short)0;
    short8 ones = {ov, ov, ov, ov, ov, ov, ov, ov};

    for (int st = 0; st < 8; st++) {
        int nbase = nchunk + st * 64;
        __syncthreads();
        for (int idx = w; idx < 8; idx += 4) {
            int nblk = idx >> 1, kt = idx & 1;
            glds16(qkvb + ((size_t)b * NSEQ + nbase + nblk * 16 + lr) * QKV_ + 512 + h * 64 + kt * 32 + lq * 8,
                   &KB[idx * 512]);
        }
        for (int idx = w; idx < 8; idx += 4) {
            int dhb = idx >> 1, nt2 = idx & 1;
            glds16(vT + ((size_t)z * 64 + dhb * 16 + lr) * NSEQ + nbase + nt2 * 32 + lq * 8,
                   &VB[idx * 512]);
        }
        __syncthreads();

        // phase A: rows n (mi 0..3), cols f' (wave w: 32 f, ni 0..1)
        float4v a2[4][2];
#pragma unroll
        for (int mi = 0; mi < 4; mi++)
#pragma unroll
            for (int ni = 0; ni < 2; ni++) a2[mi][ni] = (float4v){0.f, 0.f, 0.f, 0.f};
#pragma unroll
        for (int ks = 0; ks < 2; ks++) {
            short8 ka[4], pb[2];
#pragma unroll
            for (int mi = 0; mi < 4; mi++)
                ka[mi] = *(const short8*)&KB[((mi * 2 + ks) * 64 + l) * 8];
#pragma unroll
            for (int ni = 0; ni < 2; ni++)
                pb[ni] = *(const short8*)&PB[(((w * 2 + ni) * 2 + ks) * 64 + l) * 8];
#pragma unroll
            for (int mi = 0; mi < 4; mi++)
#pragma unroll
                for (int ni = 0; ni < 2; ni++)
                    a2[mi][ni] = __builtin_amdgcn_mfma_f32_16x16x32_bf16(ka[mi], pb[ni], a2[mi][ni], 0, 0, 0);
        }
        // exp -> bf16 -> KPA (A-frag order, local f' = w*32 + ni*16 + lr)
#pragma unroll
        for (int mi = 0; mi < 4; mi++) {
            int nb = mi * 16 + lq * 4;
            int qoff = ((nb >> 3) & 3) * 256 + (nb & 7) * 2;
            int setn = nb >> 5;
#pragma unroll
            for (int ni = 0; ni < 2; ni++) {
                int fp = w * 32 + ni * 16 + lr;
                float e0 = __expf(a2[mi][ni][0]);
                float e1 = __expf(a2[mi][ni][1]);
                float e2 = __expf(a2[mi][ni][2]);
                float e3 = __expf(a2[mi][ni][3]);
                uint2 p; p.x = pack2bf(e0, e1); p.y = pack2bf(e2, e3);
                *(uint2*)((char*)KPA + (size_t)(((fp >> 4) * 2 + setn) * 1024 + qoff + (fp & 15) * 16)) = p;
            }
        }
        // phase B: rows f' (wave w: mi 0..1), cols dh_ext (ni; ni=4 -> ksum)
#pragma unroll
        for (int ks = 0; ks < 2; ks++) {
            short8 af[2], bf[4];
#pragma unroll
            for (int mi = 0; mi < 2; mi++)
                af[mi] = *(const short8*)&KPA[(((w * 2 + mi) * 2 + ks) * 64 + l) * 8];
#pragma unroll
            for (int ni = 0; ni < 4; ni++)
                bf[ni] = *(const short8*)&VB[((ni * 2 + ks) * 64 + l) * 8];
#pragma unroll
            for (int mi = 0; mi < 2; mi++) {
#pragma unroll
                for (int ni = 0; ni < 4; ni++)
                    acc[mi][ni] = __builtin_amdgcn_mfma_f32_16x16x32_bf16(af[mi], bf[ni], acc[mi][ni], 0, 0, 0);
                acc[mi][4] = __builtin_amdgcn_mfma_f32_16x16x32_bf16(af[mi], ones, acc[mi][4], 0, 0, 0);
            }
        }
    }
    unsigned short* base = partial + (size_t)(s * 16 + z) * 80 * 256 + fh * 128;
#pragma unroll
    for (int mi = 0; mi < 2; mi++) {
        int f0r = w * 32 + mi * 16 + lq * 4;
#pragma unroll
        for (int ni = 0; ni < 5; ni++) {
            int col = ni * 16 + lr;
#pragma unroll
            for (int r = 0; r < 4; r++)
                base[(size_t)col * 256 + f0r + r] = f2bf(acc[mi][ni][r]);
        }
    }
}

// ---------------------------------------------------------------------------
// Reduce split-K bf16 partials (16 splits) -> ctxT bf16 [z][80][256].
// ---------------------------------------------------------------------------
__global__ __launch_bounds__(256) void ctx_reduce(const unsigned short* __restrict__ partial,
                                                  unsigned short* __restrict__ ctxT) {
    int idx8 = blockIdx.x * 256 + threadIdx.x;   // 0 .. 40959
    const int INNER = 16 * 80 * 256;
    size_t off = (size_t)idx8 * 8;
    float s0 = 0.f, s1 = 0.f, s2 = 0.f, s3 = 0.f, s4 = 0.f, s5 = 0.f, s6 = 0.f, s7 = 0.f;
#pragma unroll
    for (int k = 0; k < 16; k++) {
        ushort8v v = *(const ushort8v*)(partial + (size_t)k * INNER + off);
        s0 += bf2f(v[0]); s1 += bf2f(v[1]); s2 += bf2f(v[2]); s3 += bf2f(v[3]);
        s4 += bf2f(v[4]); s5 += bf2f(v[5]); s6 += bf2f(v[6]); s7 += bf2f(v[7]);
    }
    ushort8v o;
    o[0] = f2bf(s0); o[1] = f2bf(s1); o[2] = f2bf(s2); o[3] = f2bf(s3);
    o[4] = f2bf(s4); o[5] = f2bf(s5); o[6] = f2bf(s6); o[7] = f2bf(s7);
    *(ushort8v*)(ctxT + off) = o;
}

// ---------------------------------------------------------------------------
// Fused q' featuremap + (q'.ctx_ext) with D at col 64 -> bf16 attn out.
// (round-7 verified version, unchanged)
// ---------------------------------------------------------------------------
__global__ __launch_bounds__(256) void attn_fused_mfma(
    const unsigned short* __restrict__ qkvb,
    const unsigned short* __restrict__ projb,
    const unsigned short* __restrict__ ctxT,
    unsigned short* __restrict__ attnb)
{
    __shared__ __align__(16) unsigned short QB[16 * 512];
    __shared__ __align__(16) unsigned short PA[8 * 512];
    __shared__ __align__(16) unsigned short QPA[16 * 512];
    __shared__ __align__(16) unsigned short CB[10 * 512];
    const int t = threadIdx.x, w = t >> 6, l = t & 63;
    const int lr = l & 15, lq = l >> 4;
    const int m0 = blockIdx.x * 128, z = blockIdx.y;
    const int b = z >> 3, h = z & 7;

    for (int idx = w; idx < 16; idx += 4) {
        int mblk = idx >> 1, kt = idx & 1;
        glds16(qkvb + ((size_t)b * NSEQ + m0 + mblk * 16 + lr) * QKV_ + h * 64 + kt * 32 + lq * 8,
               &QB[idx * 512]);
    }
    float4v acc[2][5];
#pragma unroll
    for (int mi = 0; mi < 2; mi++)
#pragma unroll
        for (int ni = 0; ni < 5; ni++) acc[mi][ni] = (float4v){0.f, 0.f, 0.f, 0.f};

    for (int fs = 0; fs < 4; fs++) {
        int f0 = fs * 64;
        __syncthreads();
        for (int idx = w; idx < 8; idx += 4) {
            int fb = idx >> 1, kt = idx & 1;
            glds16(projb + (size_t)(f0 + fb * 16 + lr) * 64 + kt * 32 + lq * 8, &PA[idx * 512]);
        }
        for (int idx = w; idx < 10; idx += 4) {
            int dhb = idx >> 1, ft = idx & 1;
            glds16(ctxT + ((size_t)z * 80 + dhb * 16 + lr) * 256 + f0 + ft * 32 + lq * 8,
                   &CB[idx * 512]);
        }
        __syncthreads();

        float4v a2[4][2];
#pragma unroll
        for (int mi = 0; mi < 4; mi++)
#pragma unroll
            for (int ni = 0; ni < 2; ni++) a2[mi][ni] = (float4v){0.f, 0.f, 0.f, 0.f};
#pragma unroll
        for (int ks = 0; ks < 2; ks++) {
            short8 pa[4], qb[2];
#pragma unroll
            for (int mi = 0; mi < 4; mi++)
                pa[mi] = *(const short8*)&PA[((mi * 2 + ks) * 64 + l) * 8];
#pragma unroll
            for (int ni = 0; ni < 2; ni++)
                qb[ni] = *(const short8*)&QB[(((w * 2 + ni) * 2 + ks) * 64 + l) * 8];
#pragma unroll
            for (int mi = 0; mi < 4; mi++)
#pragma unroll
                for (int ni = 0; ni < 2; ni++)
                    a2[mi][ni] = __builtin_amdgcn_mfma_f32_16x16x32_bf16(pa[mi], qb[ni], a2[mi][ni], 0, 0, 0);
        }
#pragma unroll
        for (int mi = 0; mi < 4; mi++) {
            int fb2 = mi * 16 + lq * 4;
            int qoff = ((fb2 >> 3) & 3) * 256 + (fb2 & 7) * 2;
            int setf = fb2 >> 5;
#pragma unroll
            for (int ni = 0; ni < 2; ni++) {
                int m = w * 32 + ni * 16 + lr;
                float e0 = __expf(0.125f * a2[mi][ni][0]);
                float e1 = __expf(0.125f * a2[mi][ni][1]);
                float e2 = __expf(0.125f * a2[mi][ni][2]);
                float e3 = __expf(0.125f * a2[mi][ni][3]);
                uint2 p; p.x = pack2bf(e0, e1); p.y = pack2bf(e2, e3);
                *(uint2*)((char*)QPA + (size_t)(((m >> 4) * 2 + setf) * 1024 + qoff + (m & 15) * 16)) = p;
            }
        }
#pragma unroll
        for (int ks = 0; ks < 2; ks++) {
            short8 af[2], cb[5];
#pragma unroll
            for (int mi = 0; mi < 2; mi++)
                af[mi] = *(const short8*)&QPA[(((w * 2 + mi) * 2 + ks) * 64 + l) * 8];
#pragma unroll
            for (int ni = 0; ni < 5; ni++)
                cb[ni] = *(const short8*)&CB[((ni * 2 + ks) * 64 + l) * 8];
#pragma unroll
            for (int mi = 0; mi < 2; mi++)
#pragma unroll
                for (int ni = 0; ni < 5; ni++)
                    acc[mi][ni] = __builtin_amdgcn_mfma_f32_16x16x32_bf16(af[mi], cb[ni], acc[mi][ni], 0, 0, 0);
        }
    }
#pragma unroll
    for (int mi = 0; mi < 2; mi++) {
        int rowb = m0 + w * 32 + mi * 16 + lq * 4;
#pragma unroll
        for (int r = 0; r < 4; r++) {
            float dv = __shfl(acc[mi][4][r], (l & 48), 64);
            float rinv = 1.f / (dv + 1e-6f);
#pragma unroll
            for (int ni = 0; ni < 4; ni++)
                attnb[((size_t)b * NSEQ + rowb + r) * 512 + h * 64 + ni * 16 + lr] =
                    f2bf(acc[mi][ni][r] * rinv);
        }
    }
}

// ---------------------------------------------------------------------------
extern "C" void kernel_launch(void* const* d_in, const int* in_sizes, int n_in,
                              void* d_out, int out_size, void* d_ws, size_t ws_size,
                              hipStream_t stream) {
    const float* x    = (const float*)d_in[0];
    const float* Wqkv = (const float*)d_in[1];
    const float* Wout = (const float*)d_in[2];
    const float* bout = (const float*)d_in[3];
    const float* proj = (const float*)d_in[4];

    unsigned short* qkvb    = (unsigned short*)d_ws;                 // 25,165,824 u16
    unsigned short* vT      = qkvb + (size_t)M_ * QKV_;              // 8,388,608 u16
    unsigned short* partial = vT + (size_t)16 * 64 * NSEQ;           // 5,242,880 u16 (bf16, 16 splits)
    unsigned short* ctxT    = partial + (size_t)16 * 16 * 80 * 256;  // 327,680 u16
    unsigned short* projb   = ctxT + (size_t)16 * 80 * 256;          // 16,384 u16
    unsigned short* xb      = projb + 16384;                         // 8,388,608 u16
    unsigned short* attnb   = xb;                                    // overlay (xb dead after gemm1)
    unsigned short* wqkvb   = xb + (size_t)M_ * DIM_;                // 786,432 u16
    unsigned short* woutb   = wqkvb + (size_t)QKV_ * DIM_;           // 262,144 u16
    float* outp = (float*)d_out;                                     // total ws ~97 MB

    // 0) fp32 -> bf16 (single launch)
    cvt_all<<<dim3(4616), 256, 0, stream>>>(x, Wqkv, Wout, proj, xb, wqkvb, woutb, projb);
    // 1) qkv = x @ Wqkv^T — Q/K cols -> qkvb, V cols -> vT (fused transpose)
    gemm_nt_pp<true><<<dim3(QKV_ / 128, M_ / 128), 256, 0, stream>>>(xb, wqkvb, nullptr, qkvb, vT, M_, QKV_, DIM_);
    // 2) fused k' + context partials (16 splits, 8 n-steps/block)
    ctx_fused_mfma<<<dim3(16, 2, 16), 256, 0, stream>>>(qkvb, projb, vT, partial);
    // 3) reduce -> ctxT bf16 (incl. ksum row)
    ctx_reduce<<<dim3(160), 256, 0, stream>>>(partial, ctxT);
    // 4) fused q' + attention out (MFMA), bf16
    attn_fused_mfma<<<dim3(64, 16), 256, 0, stream>>>(qkvb, projb, ctxT, attnb);
    // 5) out = attn @ Wout^T + bout
    gemm_nt_pp<false><<<dim3(DIM_ / 128, M_ / 128), 256, 0, stream>>>(attnb, woutb, bout, outp, nullptr, M_, DIM_, DIM_);
}